// Round 4
// baseline (494.449 us; speedup 1.0000x reference)
//
#include <hip/hip_runtime.h>

// ---------------------------------------------------------------------------
// MoE forward, tied router: only experts 0,1 matter (weight 0.5 each),
// ent_loss = 1.5*ln(2) constant.
// bf16 intermediates. Big GEMMs (L1/L2/L3): m201-style fine-phase schedule:
//   - 16x16x32 bf16 MFMA, 8 waves (2M x 4N), per-wave 128 x (BN/4), BK=64.
//   - 4 phases per K-tile, 16 MFMA each (quadrants (m0,n0),(m0,n1),(m1,n1),
//     (m1,n0)); A-half frags reused across 2 phases, B-halves across 0<->3.
//   - staging in 16KB chunks, one per phase, staggered one phase early:
//       ph0: B0(t+1), ph1: A1(t+1), ph2: B1(t+1), ph3: A0(t+2) -> buf[cur]
//     (legal: ph2's lgkm0+barrier retired all A-reads of tile t).
//   - ONE counted vmcnt(2) per K-tile at the boundary: retires tile t+1
//     fully, keeps A0(t+2) in flight -> queue never drains (T4).
//   - LDS 16B-chunk swizzle: slot (row, p) holds logical chunk p ^ (row&7);
//     realized by pre-swizzling the GLOBAL source address (global_load_lds
//     writes linearly), read side applies the same XOR (involution).
// Out-GEMM stays on the simple 2-barrier 32x32 template (tiny).
// ---------------------------------------------------------------------------

typedef __attribute__((ext_vector_type(8))) short short8;
typedef __attribute__((ext_vector_type(4))) float f32x4;
typedef __attribute__((ext_vector_type(16))) float f32x16;

static __device__ __forceinline__ unsigned short f2bf(float f) {
  union { float f; unsigned u; } a; a.f = f;
  unsigned u = a.u;
  u += 0x7FFFu + ((u >> 16) & 1u);   // round-to-nearest-even
  return (unsigned short)(u >> 16);
}

static __device__ __forceinline__ float bf2f(unsigned short u) {
  union { float f; unsigned u; } a; a.u = ((unsigned)u) << 16;
  return a.f;
}

static __device__ __forceinline__ float gelu_erf(float v) {
  return 0.5f * v * (1.0f + erff(v * 0.70710678118654752f));
}

// ---------------------------------------------------------------------------
// f32 -> bf16 elementwise (x conversion)
// ---------------------------------------------------------------------------
__global__ __launch_bounds__(256) void cvt_kernel(const float* __restrict__ X,
                                                  unsigned short* __restrict__ XB) {
  size_t i = (size_t)blockIdx.x * 256 + threadIdx.x;
  const float4* X4 = (const float4*)X;
  float4 f = X4[i];
  ushort4 u;
  u.x = f2bf(f.x); u.y = f2bf(f.y); u.z = f2bf(f.z); u.w = f2bf(f.w);
  *(ushort4*)(XB + 4 * i) = u;
}

// ---------------------------------------------------------------------------
// Transpose + convert: in f32 [K,N] row-major -> out bf16 [N,K] row-major.
// ---------------------------------------------------------------------------
__global__ __launch_bounds__(256) void transpose_cvt(const float* __restrict__ in,
                                                     unsigned short* __restrict__ outp,
                                                     int K, int N) {
  __shared__ float tile[32][33];
  size_t base = (size_t)blockIdx.z * (size_t)K * (size_t)N;
  int k0 = blockIdx.y * 32, n0 = blockIdx.x * 32;
  int tx = threadIdx.x, ty = threadIdx.y;  // 32 x 8
#pragma unroll
  for (int j = 0; j < 32; j += 8)
    tile[ty + j][tx] = in[base + (size_t)(k0 + ty + j) * N + n0 + tx];
  __syncthreads();
#pragma unroll
  for (int j = 0; j < 32; j += 8)
    outp[base + (size_t)(n0 + ty + j) * K + k0 + tx] = f2bf(tile[tx][ty + j]);
}

// ---------------------------------------------------------------------------
// Fine-phase GEMM (16x16x32): C[m,n] = bf16( sum_k A[m,k]*Bt[n,k] + bias[n] ).
// A [M,K] bf16, Bt [N,K] bf16. 512 threads = 8 waves (2M x 4N).
// BM=256 fixed; per-wave tile 128 x (BN/4). blockIdx.z = expert.
// KD is a template parameter so staging offsets fold to immediates.
// ---------------------------------------------------------------------------
template <int BN, int KD>
__global__ __launch_bounds__(512, 2) void gemm_fine(
    const unsigned short* __restrict__ A, const unsigned short* __restrict__ Bt,
    const float* __restrict__ bias, unsigned short* __restrict__ C,
    int N, long sA, long sB, long sBias, long sC) {
  constexpr int BM = 256;
  constexpr int WNE = BN / 4;              // per-wave N extent (64 or 32)
  constexpr int NB = WNE / 16;             // B frag-cols per wave (4 or 2)
  constexpr int NBH = NB / 2;              // B frag-cols per n-half (2 or 1)
  constexpr int IA = BM / 64;              // A gload instrs per K-tile (4)
  constexpr int IB = BN / 64;              // B gload instrs per K-tile (4 or 2)
  constexpr int IAH = IA / 2, IBH = IB / 2;
  constexpr int BUFS = (BM + BN) * 64;     // shorts per K-tile buffer
  constexpr int NT = KD / 64;              // K-tiles
  static_assert(NT >= 4, "pipeline needs >=4 K-tiles");

  __shared__ unsigned short lds[2 * BUFS];

  int e = blockIdx.z;
  A += (size_t)e * sA;
  Bt += (size_t)e * sB;
  bias += (size_t)e * sBias;
  C += (size_t)e * sC;

  const int t = threadIdx.x;
  const int l = t & 63, w = t >> 6;
  const int wr = w >> 2, wc = w & 3;       // 2 x 4 wave grid
  const int lr16 = l & 15, kq = l >> 4, s7 = l & 7;
  const int bm0 = blockIdx.x * BM, bn0 = blockIdx.y * BN;

  // Staging: thread t covers LDS slot (row = j*64 + (t>>3), physchunk = t&7),
  // which must hold logical chunk (t&7) ^ ((t>>3)&7)  [row&7 == (t>>3)&7].
  const unsigned short* aS =
      A + (size_t)(bm0 + (t >> 3)) * KD + (((t & 7) ^ ((t >> 3) & 7)) << 3);
  const unsigned short* bS =
      Bt + (size_t)(bn0 + (t >> 3)) * KD + (((t & 7) ^ ((t >> 3) & 7)) << 3);
  unsigned short* aD = lds + t * 8;             // + buf*BUFS + j*4096 (linear)
  unsigned short* bD = lds + BM * 64 + t * 8;

  // Stage one 16KB chunk (IAH/IBH instrs) of A or B rows [j0*64, ...).
  auto stageCA = [&](int buf, int kt, int j0) {
#pragma unroll
    for (int j = 0; j < IAH; ++j)
      __builtin_amdgcn_global_load_lds(
          (const __attribute__((address_space(1))) void*)(aS + (size_t)((j0 + j) * 64) * KD + kt * 64),
          (__attribute__((address_space(3))) void*)(aD + buf * BUFS + (j0 + j) * 4096), 16, 0, 0);
  };
  auto stageCB = [&](int buf, int kt, int j0) {
#pragma unroll
    for (int j = 0; j < IBH; ++j)
      __builtin_amdgcn_global_load_lds(
          (const __attribute__((address_space(1))) void*)(bS + (size_t)((j0 + j) * 64) * KD + kt * 64),
          (__attribute__((address_space(3))) void*)(bD + buf * BUFS + (j0 + j) * 4096), 16, 0, 0);
  };

  // Frag read swizzle: logical chunk q = ks*4 + kq; phys = q ^ (row&7), row&7==s7.
  int coff[2];
#pragma unroll
  for (int ks = 0; ks < 2; ++ks) coff[ks] = ((ks * 4 + kq) ^ s7) << 3;

  f32x4 acc[8][NB];
#pragma unroll
  for (int i = 0; i < 8; ++i)
#pragma unroll
    for (int j = 0; j < NB; ++j)
#pragma unroll
      for (int r = 0; r < 4; ++r) acc[i][j][r] = 0.f;

  // Prologue: tile 0 fully issued + A0-chunk of tile 1; retire tile 0 only.
  stageCA(0, 0, 0); stageCB(0, 0, 0); stageCA(0, 0, IAH); stageCB(0, 0, IBH);
  stageCA(1, 1, 0);
  asm volatile("s_waitcnt vmcnt(%0)" ::"n"(IAH) : "memory");
  __builtin_amdgcn_s_barrier();
  __builtin_amdgcn_sched_barrier(0);

  short8 aa[4][2], bb[2][NBH][2];

#pragma unroll 2
  for (int kt = 0; kt < NT; ++kt) {
    const int cur = kt & 1;
    const unsigned short* Ab = lds + cur * BUFS + (wr * 128 + lr16) * 64;
    const unsigned short* Bb = lds + cur * BUFS + BM * 64 + (wc * WNE + lr16) * 64;

    // ---- phase 0: quadrant (m0, n0); stage B0(kt+1) -----------------------
#pragma unroll
    for (int fr = 0; fr < 4; ++fr)
#pragma unroll
      for (int ks = 0; ks < 2; ++ks)
        aa[fr][ks] = *(const short8*)(Ab + fr * 1024 + coff[ks]);
#pragma unroll
    for (int fc = 0; fc < NBH; ++fc)
#pragma unroll
      for (int ks = 0; ks < 2; ++ks)
        bb[0][fc][ks] = *(const short8*)(Bb + fc * 1024 + coff[ks]);
    if (kt + 1 < NT) stageCB(cur ^ 1, kt + 1, 0);
    __builtin_amdgcn_s_barrier();
    asm volatile("s_waitcnt lgkmcnt(0)" ::: "memory");
    __builtin_amdgcn_sched_barrier(0);
    __builtin_amdgcn_s_setprio(1);
#pragma unroll
    for (int ks = 0; ks < 2; ++ks)
#pragma unroll
      for (int fr = 0; fr < 4; ++fr)
#pragma unroll
        for (int fc = 0; fc < NBH; ++fc)
          acc[fr][fc] = __builtin_amdgcn_mfma_f32_16x16x32_bf16(aa[fr][ks], bb[0][fc][ks], acc[fr][fc], 0, 0, 0);
    __builtin_amdgcn_s_setprio(0);
    __builtin_amdgcn_sched_barrier(0);
    __builtin_amdgcn_s_barrier();

    // ---- phase 1: quadrant (m0, n1); stage A1(kt+1) -----------------------
#pragma unroll
    for (int fc = 0; fc < NBH; ++fc)
#pragma unroll
      for (int ks = 0; ks < 2; ++ks)
        bb[1][fc][ks] = *(const short8*)(Bb + (WNE / 2 + fc * 16) * 64 + coff[ks]);
    if (kt + 1 < NT) stageCA(cur ^ 1, kt + 1, IAH);
    __builtin_amdgcn_s_barrier();
    asm volatile("s_waitcnt lgkmcnt(0)" ::: "memory");
    __builtin_amdgcn_sched_barrier(0);
    __builtin_amdgcn_s_setprio(1);
#pragma unroll
    for (int ks = 0; ks < 2; ++ks)
#pragma unroll
      for (int fr = 0; fr < 4; ++fr)
#pragma unroll
        for (int fc = 0; fc < NBH; ++fc)
          acc[fr][NBH + fc] = __builtin_amdgcn_mfma_f32_16x16x32_bf16(aa[fr][ks], bb[1][fc][ks], acc[fr][NBH + fc], 0, 0, 0);
    __builtin_amdgcn_s_setprio(0);
    __builtin_amdgcn_sched_barrier(0);
    __builtin_amdgcn_s_barrier();

    // ---- phase 2: quadrant (m1, n1); A regs overwritten; stage B1(kt+1) ---
#pragma unroll
    for (int fr = 0; fr < 4; ++fr)
#pragma unroll
      for (int ks = 0; ks < 2; ++ks)
        aa[fr][ks] = *(const short8*)(Ab + (64 + fr * 16) * 64 + coff[ks]);
    if (kt + 1 < NT) stageCB(cur ^ 1, kt + 1, IBH);
    __builtin_amdgcn_s_barrier();
    asm volatile("s_waitcnt lgkmcnt(0)" ::: "memory");  // all buf[cur] reads done
    __builtin_amdgcn_sched_barrier(0);
    __builtin_amdgcn_s_setprio(1);
#pragma unroll
    for (int ks = 0; ks < 2; ++ks)
#pragma unroll
      for (int fr = 0; fr < 4; ++fr)
#pragma unroll
        for (int fc = 0; fc < NBH; ++fc)
          acc[4 + fr][NBH + fc] = __builtin_amdgcn_mfma_f32_16x16x32_bf16(aa[fr][ks], bb[1][fc][ks], acc[4 + fr][NBH + fc], 0, 0, 0);
    __builtin_amdgcn_s_setprio(0);
    __builtin_amdgcn_sched_barrier(0);
    __builtin_amdgcn_s_barrier();   // all waves past A-reads: A-half of buf[cur] reusable

    // ---- phase 3: quadrant (m1, n0), read-free; stage A0(kt+2) into cur ---
    if (kt + 2 < NT) stageCA(cur, kt + 2, 0);
    __builtin_amdgcn_s_setprio(1);
#pragma unroll
    for (int ks = 0; ks < 2; ++ks)
#pragma unroll
      for (int fr = 0; fr < 4; ++fr)
#pragma unroll
        for (int fc = 0; fc < NBH; ++fc)
          acc[4 + fr][fc] = __builtin_amdgcn_mfma_f32_16x16x32_bf16(aa[fr][ks], bb[0][fc][ks], acc[4 + fr][fc], 0, 0, 0);
    __builtin_amdgcn_s_setprio(0);

    // ---- K-tile boundary: counted vmcnt retires B0,A1,B1(kt+1), keeps
    // A0(kt+2) in flight; barrier makes it visible to all waves -------------
    if (kt + 1 < NT) {
      __builtin_amdgcn_sched_barrier(0);
      if (kt + 2 < NT)
        asm volatile("s_waitcnt vmcnt(%0)" ::"n"(IAH) : "memory");
      else
        asm volatile("s_waitcnt vmcnt(0)" ::: "memory");
      __builtin_amdgcn_s_barrier();
      __builtin_amdgcn_sched_barrier(0);
    }
  }

  // Epilogue: 16x16 C/D layout: col = lane&15, row = (lane>>4)*4 + reg.
  const int m0 = bm0 + wr * 128 + kq * 4;
  const int n0c = bn0 + wc * WNE + lr16;
#pragma unroll
  for (int fn = 0; fn < NB; ++fn) {
    int nn = n0c + fn * 16;
    float bv = bias[nn];
#pragma unroll
    for (int fm = 0; fm < 8; ++fm) {
#pragma unroll
      for (int r = 0; r < 4; ++r) {
        int m = m0 + fm * 16 + r;
        C[(size_t)m * N + nn] = f2bf(acc[fm][fn][r] + bv);
      }
    }
  }
}

// ---------------------------------------------------------------------------
// Simple GEMM (kept for the small Out layer): C = bf16(A@Bt^T + bias).
// BM x BN tile, BK=32, 256 threads = 4 waves, 32x32x16 MFMA, chunk swizzle.
// ---------------------------------------------------------------------------
template <int BM, int BN, int WR, int WC>
__global__ __launch_bounds__(256) void gemm_bias(
    const unsigned short* __restrict__ A, const unsigned short* __restrict__ Bt,
    const float* __restrict__ bias, unsigned short* __restrict__ C,
    int N, int K, long sA, long sB, long sBias, long sC) {
  constexpr int TM = BM / WR, TN = BN / WC;   // per-wave tile
  constexpr int IM = TM / 32, JN = TN / 32;   // 32x32 frags per wave
  int e = blockIdx.z;
  A += (size_t)e * sA;
  Bt += (size_t)e * sB;
  bias += (size_t)e * sBias;
  C += (size_t)e * sC;

  __shared__ unsigned short As[BM * 32];
  __shared__ unsigned short Bs[BN * 32];

  int t = threadIdx.x;
  int wave = t >> 6, lane = t & 63;
  int wr = wave / WC, wc = wave % WC;
  int lrow = lane & 31;        // row within 32x32 frag
  int h = lane >> 5;           // k-half selector
  int lsw = (lrow >> 1) & 3;   // row swizzle key

  int srow = t >> 2;
  int schunk = (t & 3) ^ ((t >> 3) & 3);
  const unsigned short* ag = A + (size_t)(blockIdx.x * BM + srow) * K + schunk * 8;
  const unsigned short* bg = Bt + (size_t)(blockIdx.y * BN + srow) * K + schunk * 8;
  unsigned short* al = As + t * 8;
  unsigned short* bl = Bs + t * 8;

  f32x16 acc[IM][JN];
#pragma unroll
  for (int i = 0; i < IM; i++)
#pragma unroll
    for (int j = 0; j < JN; j++)
#pragma unroll
      for (int r = 0; r < 16; r++) acc[i][j][r] = 0.f;

  int nk = K >> 5;
  for (int kt = 0; kt < nk; ++kt) {
    __syncthreads();
#pragma unroll
    for (int c = 0; c < BM / 64; ++c)
      __builtin_amdgcn_global_load_lds(
          (const __attribute__((address_space(1))) void*)(ag + (size_t)(64 * c) * K),
          (__attribute__((address_space(3))) void*)(al + 64 * c * 32), 16, 0, 0);
#pragma unroll
    for (int c = 0; c < BN / 64; ++c)
      __builtin_amdgcn_global_load_lds(
          (const __attribute__((address_space(1))) void*)(bg + (size_t)(64 * c) * K),
          (__attribute__((address_space(3))) void*)(bl + 64 * c * 32), 16, 0, 0);
    ag += 32;
    bg += 32;
    __syncthreads();

#pragma unroll
    for (int s = 0; s < 2; ++s) {
      int pc = ((2 * s + h) ^ lsw) * 8;
      short8 af[IM], bf[JN];
#pragma unroll
      for (int i = 0; i < IM; i++)
        af[i] = *(const short8*)(As + (wr * TM + i * 32 + lrow) * 32 + pc);
#pragma unroll
      for (int j = 0; j < JN; j++)
        bf[j] = *(const short8*)(Bs + (wc * TN + j * 32 + lrow) * 32 + pc);
#pragma unroll
      for (int i = 0; i < IM; i++)
#pragma unroll
        for (int j = 0; j < JN; j++)
          acc[i][j] = __builtin_amdgcn_mfma_f32_32x32x16_bf16(af[i], bf[j], acc[i][j], 0, 0, 0);
    }
  }

  int m0 = blockIdx.x * BM + wr * TM + 4 * h;
  int n0 = blockIdx.y * BN + wc * TN + lrow;
#pragma unroll
  for (int j = 0; j < JN; j++) {
    int n = n0 + j * 32;
    float bv = bias[n];
#pragma unroll
    for (int i = 0; i < IM; i++) {
#pragma unroll
      for (int r = 0; r < 16; r++) {
        int m = m0 + i * 32 + (r & 3) + 8 * (r >> 2);
        C[(size_t)m * N + n] = f2bf(acc[i][j][r] + bv);
      }
    }
  }
}

// ---------------------------------------------------------------------------
// gelu + row LayerNorm, bf16 in -> bf16 out. grid (B, E), 256 thr, N=256*NPT.
// ---------------------------------------------------------------------------
template <int NPT>
__global__ __launch_bounds__(256) void gelu_ln(const unsigned short* __restrict__ T,
                                               const float* __restrict__ g,
                                               const float* __restrict__ be,
                                               unsigned short* __restrict__ H,
                                               long sT, long sH, int sP) {
  typedef short vecS __attribute__((ext_vector_type(NPT)));
  constexpr int N = 256 * NPT;
  int e = blockIdx.y;
  size_t row = blockIdx.x;
  int t = threadIdx.x;
  const unsigned short* tp = T + (size_t)e * sT + row * N + t * NPT;
  const float* gp = g + (size_t)e * sP + t * NPT;
  const float* bp = be + (size_t)e * sP + t * NPT;
  unsigned short* hp = H + (size_t)e * sH + row * N + t * NPT;

  vecS rv = *(const vecS*)tp;
  float v[NPT], s = 0.f, q = 0.f;
#pragma unroll
  for (int i = 0; i < NPT; i++) {
    v[i] = gelu_erf(bf2f((unsigned short)rv[i]));
    s += v[i];
    q += v[i] * v[i];
  }
#pragma unroll
  for (int off = 32; off > 0; off >>= 1) {
    s += __shfl_down(s, off, 64);
    q += __shfl_down(q, off, 64);
  }
  __shared__ float rs[4], rq[4];
  int wv = t >> 6;
  if ((t & 63) == 0) { rs[wv] = s; rq[wv] = q; }
  __syncthreads();
  s = rs[0] + rs[1] + rs[2] + rs[3];
  q = rq[0] + rq[1] + rq[2] + rq[3];
  float m = s * (1.f / N);
  float rstd = rsqrtf(q * (1.f / N) - m * m + 1e-5f);
  vecS ov;
#pragma unroll
  for (int i = 0; i < NPT; i++)
    ov[i] = (short)f2bf((v[i] - m) * rstd * gp[i] + bp[i]);
  *(vecS*)hp = ov;
}

// ---------------------------------------------------------------------------
// gelu + LN both experts' t3 rows + combine 0.5*(a+b) -> bf16. N=1024 fixed.
// ---------------------------------------------------------------------------
__global__ __launch_bounds__(256) void ln3_combine(const unsigned short* __restrict__ T,
                                                   const float* __restrict__ g,
                                                   const float* __restrict__ be,
                                                   unsigned short* __restrict__ CB) {
  size_t row = blockIdx.x;
  int t = threadIdx.x;
  const unsigned short* t0 = T + row * 1024 + t * 4;
  const unsigned short* t1 = T + (size_t)4096 * 1024 + row * 1024 + t * 4;
  ushort4 r0 = *(const ushort4*)t0;
  ushort4 r1 = *(const ushort4*)t1;
  float v0[4], v1[4];
  v0[0] = gelu_erf(bf2f(r0.x)); v0[1] = gelu_erf(bf2f(r0.y));
  v0[2] = gelu_erf(bf2f(r0.z)); v0[3] = gelu_erf(bf2f(r0.w));
  v1[0] = gelu_erf(bf2f(r1.x)); v1[1] = gelu_erf(bf2f(r1.y));
  v1[2] = gelu_erf(bf2f(r1.z)); v1[3] = gelu_erf(bf2f(r1.w));
  float s0 = 0.f, q0 = 0.f, s1 = 0.f, q1 = 0.f;
#pragma unroll
  for (int i = 0; i < 4; i++) {
    s0 += v0[i]; q0 += v0[i] * v0[i];
    s1 += v1[i]; q1 += v1[i] * v1[i];
  }
#pragma unroll
  for (int off = 32; off > 0; off >>= 1) {
    s0 += __shfl_down(s0, off, 64); q0 += __shfl_down(q0, off, 64);
    s1 += __shfl_down(s1, off, 64); q1 += __shfl_down(q1, off, 64);
  }
  __shared__ float r[4][4];
  int wv = t >> 6;
  if ((t & 63) == 0) { r[0][wv] = s0; r[1][wv] = q0; r[2][wv] = s1; r[3][wv] = q1; }
  __syncthreads();
  s0 = r[0][0] + r[0][1] + r[0][2] + r[0][3];
  q0 = r[1][0] + r[1][1] + r[1][2] + r[1][3];
  s1 = r[2][0] + r[2][1] + r[2][2] + r[2][3];
  q1 = r[3][0] + r[3][1] + r[3][2] + r[3][3];
  float m0 = s0 * (1.f / 1024.f), m1 = s1 * (1.f / 1024.f);
  float rs0 = rsqrtf(q0 * (1.f / 1024.f) - m0 * m0 + 1e-5f);
  float rs1 = rsqrtf(q1 * (1.f / 1024.f) - m1 * m1 + 1e-5f);
  int n = t * 4;
  ushort4 o;
  float a, b;
  a = (v0[0] - m0) * rs0 * g[n + 0] + be[n + 0];
  b = (v1[0] - m1) * rs1 * g[1024 + n + 0] + be[1024 + n + 0];
  o.x = f2bf(0.5f * (a + b));
  a = (v0[1] - m0) * rs0 * g[n + 1] + be[n + 1];
  b = (v1[1] - m1) * rs1 * g[1024 + n + 1] + be[1024 + n + 1];
  o.y = f2bf(0.5f * (a + b));
  a = (v0[2] - m0) * rs0 * g[n + 2] + be[n + 2];
  b = (v1[2] - m1) * rs1 * g[1024 + n + 2] + be[1024 + n + 2];
  o.z = f2bf(0.5f * (a + b));
  a = (v0[3] - m0) * rs0 * g[n + 3] + be[n + 3];
  b = (v1[3] - m1) * rs1 * g[1024 + n + 3] + be[1024 + n + 3];
  o.w = f2bf(0.5f * (a + b));
  *(ushort4*)(CB + row * 1024 + n) = o;
}

// ---------------------------------------------------------------------------
// Final gelu + LN (bf16 in -> f32 out) + ent_loss constant. N=512 fixed.
// ---------------------------------------------------------------------------
__global__ __launch_bounds__(256) void lno_kernel(const unsigned short* __restrict__ T,
                                                  const float* __restrict__ g,
                                                  const float* __restrict__ be,
                                                  float* __restrict__ out) {
  size_t row = blockIdx.x;
  int t = threadIdx.x;
  const unsigned short* tp = T + row * 512 + t * 2;
  ushort2 rv = *(const ushort2*)tp;
  float v[2];
  v[0] = gelu_erf(bf2f(rv.x));
  v[1] = gelu_erf(bf2f(rv.y));
  float s = v[0] + v[1];
  float q = v[0] * v[0] + v[1] * v[1];
#pragma unroll
  for (int off = 32; off > 0; off >>= 1) {
    s += __shfl_down(s, off, 64);
    q += __shfl_down(q, off, 64);
  }
  __shared__ float rs[4], rq[4];
  int wv = t >> 6;
  if ((t & 63) == 0) { rs[wv] = s; rq[wv] = q; }
  __syncthreads();
  s = rs[0] + rs[1] + rs[2] + rs[3];
  q = rq[0] + rq[1] + rq[2] + rq[3];
  float m = s * (1.f / 512.f);
  float rstd = rsqrtf(q * (1.f / 512.f) - m * m + 1e-5f);
  int n = t * 2;
  float2 o;
  o.x = (v[0] - m) * rstd * g[n] + be[n];
  o.y = (v[1] - m) * rstd * g[n + 1] + be[n + 1];
  *(float2*)(out + row * 512 + n) = o;
  if (row == 0 && t == 0) out[(size_t)4096 * 512] = 1.03972077f;  // 1.5*ln(2)
}

// ---------------------------------------------------------------------------
extern "C" void kernel_launch(void* const* d_in, const int* in_sizes, int n_in,
                              void* d_out, int out_size, void* d_ws, size_t ws_size,
                              hipStream_t stream) {
  const float* x   = (const float*)d_in[0];
  const float* W1  = (const float*)d_in[3];
  const float* b1  = (const float*)d_in[4];
  const float* g1  = (const float*)d_in[5];
  const float* be1 = (const float*)d_in[6];
  const float* W2  = (const float*)d_in[7];
  const float* b2  = (const float*)d_in[8];
  const float* g2  = (const float*)d_in[9];
  const float* be2 = (const float*)d_in[10];
  const float* W3  = (const float*)d_in[11];
  const float* b3  = (const float*)d_in[12];
  const float* g3  = (const float*)d_in[13];
  const float* be3 = (const float*)d_in[14];
  const float* Wo  = (const float*)d_in[15];
  const float* bo  = (const float*)d_in[16];
  const float* go  = (const float*)d_in[17];
  const float* beo = (const float*)d_in[18];
  float* out = (float*)d_out;

  char* w = (char*)d_ws;
  unsigned short* xb  = (unsigned short*)(w + 0);          // 8 MB   [4096,1024]
  unsigned short* W1t = (unsigned short*)(w + 8388608);    // 8 MB   [2][2048,1024]
  unsigned short* W2t = (unsigned short*)(w + 16777216);   // 16 MB  [2][2048,2048]
  unsigned short* W3t = (unsigned short*)(w + 33554432);   // 8 MB   [2][1024,2048]
  unsigned short* Wot = (unsigned short*)(w + 41943040);   // 1 MB   [512,1024]
  unsigned short* tR  = (unsigned short*)(w + 42991616);   // 33.5MB [2][4096,2048] raw
  unsigned short* hA  = (unsigned short*)(w + 76546048);   // 33.5MB [2][4096,2048] LN'd
  unsigned short* cb  = (unsigned short*)(w + 110100480);  // 8 MB   [4096,1024]
  unsigned short* to  = (unsigned short*)(w + 118489088);  // 4 MB   [4096,512]

  dim3 tb(32, 8);
  cvt_kernel<<<4096, 256, 0, stream>>>(x, xb);
  transpose_cvt<<<dim3(64, 32, 2), tb, 0, stream>>>(W1, W1t, 1024, 2048);
  transpose_cvt<<<dim3(64, 64, 2), tb, 0, stream>>>(W2, W2t, 2048, 2048);
  transpose_cvt<<<dim3(32, 64, 2), tb, 0, stream>>>(W3, W3t, 2048, 1024);
  transpose_cvt<<<dim3(16, 32, 1), tb, 0, stream>>>(Wo, Wot, 1024, 512);

  // L1: [4096,1024]@[1024,2048] x2 experts — 256x256 tile, 256 blocks (1/CU)
  gemm_fine<256, 1024><<<dim3(16, 8, 2), 512, 0, stream>>>(
      xb, W1t, b1, tR, 2048, 0L, 2097152L, 2048L, 8388608L);
  gelu_ln<8><<<dim3(4096, 2), 256, 0, stream>>>(tR, g1, be1, hA, 8388608L, 8388608L, 2048);
  // L2: [4096,2048]@[2048,2048] x2 — 256x256 tile
  gemm_fine<256, 2048><<<dim3(16, 8, 2), 512, 0, stream>>>(
      hA, W2t, b2, tR, 2048, 8388608L, 4194304L, 2048L, 8388608L);
  gelu_ln<8><<<dim3(4096, 2), 256, 0, stream>>>(tR, g2, be2, hA, 8388608L, 8388608L, 2048);
  // L3: [4096,2048]@[2048,1024] x2 — 256x128 tile
  gemm_fine<128, 2048><<<dim3(16, 8, 2), 512, 0, stream>>>(
      hA, W3t, b3, tR, 1024, 8388608L, 2097152L, 1024L, 4194304L);
  ln3_combine<<<4096, 256, 0, stream>>>(tR, g3, be3, cb);
  // Out: [4096,1024]@[1024,512] — 128x64 tile, 256 blocks (1/CU)
  gemm_bias<128, 64, 2, 2><<<dim3(32, 8, 1), 256, 0, stream>>>(
      cb, Wot, bo, to, 512, 1024, 0L, 0L, 0L, 0L);
  lno_kernel<<<4096, 256, 0, stream>>>(to, go, beo, out);
}

// Round 5
// 489.877 us; speedup vs baseline: 1.0093x; 1.0093x over previous
//
#include <hip/hip_runtime.h>

// ---------------------------------------------------------------------------
// MoE forward, tied router: only experts 0,1 matter (weight 0.5 each),
// ent_loss = 1.5*ln(2) constant.
// bf16 intermediates. Big GEMMs (L1/L2/L3): 512-thread double-buffered
// counted-vmcnt pipeline (R3 structure) + XCD SUPERTILE REMAP:
//   - grid (16,8,2) = 256 wgs, 1/CU. flat d -> XCD c = d&7 (round-robin HW
//     mapping). XCD c owns a 4M x 8N supertile of expert (c&1):
//       e = c&1, mt = (c>>1)*4 + (k>>3), nt = k&7,  k = d>>3   (bijective)
//     Per K-tile one XCD's 32 blocks touch 4 A-chunks + 8 B-chunks = 384 KB
//     << 4 MB L2, so each chunk is fetched from L3 once per XCD and served
//     from L2 thereafter (~4x lower L3 feed demand). Without this, default
//     round-robin gives near-zero L2 reuse and the staging queue feeds from
//     L3 at ~6.6 TB/s aggregate -> stalls invariant to schedule (R1-R4 nulls).
//   - per K-tile: region1 {A frags + B half1 reads, stageB(kt+1), MFMA half1}
//     lgkm(0)+barrier, stageA(kt+2); region2 {B half2 reads under MFMA half2}
//     vmcnt(IA)+barrier (never 0 mid-loop).
//   - LDS 16B-chunk swizzle: slot (row, p) holds logical chunk p ^ (row&7);
//     realized by pre-swizzling the GLOBAL source address (global_load_lds
//     writes linearly), read side applies the same XOR (involution).
// Out-GEMM: simple 2-barrier template + same style supertile remap.
// ---------------------------------------------------------------------------

typedef __attribute__((ext_vector_type(8))) short short8;
typedef __attribute__((ext_vector_type(16))) float f32x16;

static __device__ __forceinline__ unsigned short f2bf(float f) {
  union { float f; unsigned u; } a; a.f = f;
  unsigned u = a.u;
  u += 0x7FFFu + ((u >> 16) & 1u);   // round-to-nearest-even
  return (unsigned short)(u >> 16);
}

static __device__ __forceinline__ float bf2f(unsigned short u) {
  union { float f; unsigned u; } a; a.u = ((unsigned)u) << 16;
  return a.f;
}

static __device__ __forceinline__ float gelu_erf(float v) {
  return 0.5f * v * (1.0f + erff(v * 0.70710678118654752f));
}

// ---------------------------------------------------------------------------
// f32 -> bf16 elementwise (x conversion)
// ---------------------------------------------------------------------------
__global__ __launch_bounds__(256) void cvt_kernel(const float* __restrict__ X,
                                                  unsigned short* __restrict__ XB) {
  size_t i = (size_t)blockIdx.x * 256 + threadIdx.x;
  const float4* X4 = (const float4*)X;
  float4 f = X4[i];
  ushort4 u;
  u.x = f2bf(f.x); u.y = f2bf(f.y); u.z = f2bf(f.z); u.w = f2bf(f.w);
  *(ushort4*)(XB + 4 * i) = u;
}

// ---------------------------------------------------------------------------
// Transpose + convert: in f32 [K,N] row-major -> out bf16 [N,K] row-major.
// ---------------------------------------------------------------------------
__global__ __launch_bounds__(256) void transpose_cvt(const float* __restrict__ in,
                                                     unsigned short* __restrict__ outp,
                                                     int K, int N) {
  __shared__ float tile[32][33];
  size_t base = (size_t)blockIdx.z * (size_t)K * (size_t)N;
  int k0 = blockIdx.y * 32, n0 = blockIdx.x * 32;
  int tx = threadIdx.x, ty = threadIdx.y;  // 32 x 8
#pragma unroll
  for (int j = 0; j < 32; j += 8)
    tile[ty + j][tx] = in[base + (size_t)(k0 + ty + j) * N + n0 + tx];
  __syncthreads();
#pragma unroll
  for (int j = 0; j < 32; j += 8)
    outp[base + (size_t)(n0 + ty + j) * K + k0 + tx] = f2bf(tile[tx][ty + j]);
}

// ---------------------------------------------------------------------------
// Pipelined 2-barrier read-balanced GEMM + XCD supertile remap:
//   C[m,n] = bf16( sum_k A[m,k]*Bt[n,k] + bias[n] ).
// A [M,K] bf16, Bt [N,K] bf16. 512 threads = 8 waves (WM=4 x WN=2).
// BM = 256 fixed. Per-wave tile 64 x (BN/2). GRID MUST BE (16,8,2).
// KD (K dim) is a template parameter so staging offsets fold to immediates.
// ---------------------------------------------------------------------------
template <int BN, int KD>
__global__ __launch_bounds__(512, 2) void gemm_pipe(
    const unsigned short* __restrict__ A, const unsigned short* __restrict__ Bt,
    const float* __restrict__ bias, unsigned short* __restrict__ C,
    int N, long sA, long sB, long sBias, long sC) {
  constexpr int BM = 256;
  constexpr int WNE = BN / 2;              // per-wave N extent
  constexpr int NPG = WNE / 32;            // B frags per wave (4 or 2)
  constexpr int NH = NPG / 2;              // B frags per region half
  static_assert(NH >= 1, "need at least 2 B frags");
  constexpr int IA = BM / 64;              // A gload issues per K-tile (4)
  constexpr int IB = BN / 64;              // B gload issues per K-tile
  constexpr int BUFS = (BM + BN) * 64;     // shorts per K-tile buffer
  constexpr int NT = KD / 64;              // K-tiles
  static_assert(NT >= 3, "pipeline needs >=3 K-tiles");

  __shared__ unsigned short lds[2 * BUFS];

  // ---- XCD supertile remap (grid fixed at (16,8,2), 256 wgs, nwg%8==0) ----
  // flat dispatch id -> XCD = d&7. XCD c: expert c&1, M-rows [(c>>1)*4, +4),
  // all 8 N-tiles. Bijective: d = ((mt&3)*8 + nt)*8 + (mt>>2)*2 + e.
  const int d = blockIdx.x + 16 * (blockIdx.y + 8 * blockIdx.z);
  const int xc = d & 7, kk = d >> 3;
  const int e = xc & 1;
  const int bm0 = (((xc >> 1) << 2) + (kk >> 3)) * BM;
  const int bn0 = (kk & 7) * BN;

  A += (size_t)e * sA;
  Bt += (size_t)e * sB;
  bias += (size_t)e * sBias;
  C += (size_t)e * sC;

  const int t = threadIdx.x;
  const int l = t & 63, w = t >> 6;
  const int wr = w >> 1, wc = w & 1;       // 4 x 2 wave grid
  const int lr = l & 31, h = l >> 5, s7 = l & 7;

  // Staging: thread t covers LDS slot (row = j*64 + (t>>3), physchunk = t&7),
  // which must hold logical chunk (t&7) ^ ((t>>3)&7)  [row&7 == (t>>3)&7].
  const unsigned short* aS =
      A + (size_t)(bm0 + (t >> 3)) * KD + (((t & 7) ^ ((t >> 3) & 7)) << 3);
  const unsigned short* bS =
      Bt + (size_t)(bn0 + (t >> 3)) * KD + (((t & 7) ^ ((t >> 3) & 7)) << 3);
  unsigned short* aD = lds + t * 8;             // + buf*BUFS + j*4096 (linear)
  unsigned short* bD = lds + BM * 64 + t * 8;

  auto stageA = [&](int buf, int kt) {
#pragma unroll
    for (int j = 0; j < IA; ++j)
      __builtin_amdgcn_global_load_lds(
          (const __attribute__((address_space(1))) void*)(aS + (size_t)(j * 64) * KD + kt * 64),
          (__attribute__((address_space(3))) void*)(aD + buf * BUFS + j * 4096), 16, 0, 0);
  };
  auto stageB = [&](int buf, int kt) {
#pragma unroll
    for (int j = 0; j < IB; ++j)
      __builtin_amdgcn_global_load_lds(
          (const __attribute__((address_space(1))) void*)(bS + (size_t)(j * 64) * KD + kt * 64),
          (__attribute__((address_space(3))) void*)(bD + buf * BUFS + j * 4096), 16, 0, 0);
  };

  // Frag read swizzle: logical chunk q = 2*ks + h; phys = q ^ (row&7), row&7==s7.
  int coff[4];
#pragma unroll
  for (int ks = 0; ks < 4; ++ks) coff[ks] = ((2 * ks + h) ^ s7) << 3;

  f32x16 acc[2][NPG];
#pragma unroll
  for (int i = 0; i < 2; ++i)
#pragma unroll
    for (int j = 0; j < NPG; ++j)
#pragma unroll
      for (int r = 0; r < 16; ++r) acc[i][j][r] = 0.f;

  // Prologue: A0,B0,A1 issued; wait tile 0 (A1 stays in flight).
  stageA(0, 0); stageB(0, 0); stageA(1, 1);
  asm volatile("s_waitcnt vmcnt(%0)" ::"n"(IA) : "memory");
  __builtin_amdgcn_s_barrier();
  __builtin_amdgcn_sched_barrier(0);

  short8 af[2][4], bb[NH][4];

#pragma unroll 2
  for (int kt = 0; kt < NT; ++kt) {
    const int cur = kt & 1;
    const unsigned short* Ab = lds + cur * BUFS + (wr * 64 + lr) * 64;
    const unsigned short* Bb = lds + cur * BUFS + BM * 64 + (wc * WNE + lr) * 64;

    // ======== region 1: A frags + B half-1, MFMA half-1 ====================
#pragma unroll
    for (int i = 0; i < 2; ++i)
#pragma unroll
      for (int ks = 0; ks < 4; ++ks)
        af[i][ks] = *(const short8*)(Ab + i * 2048 + coff[ks]);
#pragma unroll
    for (int j = 0; j < NH; ++j)
#pragma unroll
      for (int ks = 0; ks < 4; ++ks)
        bb[j][ks] = *(const short8*)(Bb + j * 2048 + coff[ks]);
    if (kt + 1 < NT) stageB(cur ^ 1, kt + 1);

    __builtin_amdgcn_s_setprio(1);
#pragma unroll
    for (int ks = 0; ks < 4; ++ks)
#pragma unroll
      for (int i = 0; i < 2; ++i)
#pragma unroll
        for (int j = 0; j < NH; ++j)
          acc[i][j] = __builtin_amdgcn_mfma_f32_32x32x16_bf16(af[i][ks], bb[j][ks], acc[i][j], 0, 0, 0);
    __builtin_amdgcn_s_setprio(0);

    // ---- all buf[cur] A-reads retired chip-wide; stage A(kt+2) ------------
    asm volatile("s_waitcnt lgkmcnt(0)" ::: "memory");
    __builtin_amdgcn_sched_barrier(0);
    __builtin_amdgcn_s_barrier();
    __builtin_amdgcn_sched_barrier(0);
    if (kt + 2 < NT) stageA(cur, kt + 2);

    // ======== region 2: B half-2 reads flow under MFMA half-2 ==============
#pragma unroll
    for (int j = 0; j < NH; ++j)
#pragma unroll
      for (int ks = 0; ks < 4; ++ks)
        bb[j][ks] = *(const short8*)(Bb + (NH + j) * 2048 + coff[ks]);

    __builtin_amdgcn_s_setprio(1);
#pragma unroll
    for (int ks = 0; ks < 4; ++ks)
#pragma unroll
      for (int i = 0; i < 2; ++i)
#pragma unroll
        for (int j = 0; j < NH; ++j)
          acc[i][NH + j] = __builtin_amdgcn_mfma_f32_32x32x16_bf16(af[i][ks], bb[j][ks], acc[i][NH + j], 0, 0, 0);
    __builtin_amdgcn_s_setprio(0);

    // ---- K-tile boundary: counted vmcnt (retires {A,B}(kt+1), keeps
    // A(kt+2) in flight), then barrier: buf[cur^1] ready --------------------
    if (kt + 1 < NT) {
      __builtin_amdgcn_sched_barrier(0);
      if (kt + 2 < NT)
        asm volatile("s_waitcnt vmcnt(%0)" ::"n"(IA) : "memory");
      else
        asm volatile("s_waitcnt vmcnt(0)" ::: "memory");
      __builtin_amdgcn_s_barrier();
      __builtin_amdgcn_sched_barrier(0);
    }
  }

  // Epilogue: 32x32 C/D layout: col=lane&31, row=(reg&3)+8*(reg>>2)+4*(lane>>5)
  const int m0 = bm0 + wr * 64 + 4 * h;
  const int n0c = bn0 + wc * WNE + lr;
#pragma unroll
  for (int j = 0; j < NPG; ++j) {
    int nn = n0c + j * 32;
    float bv = bias[nn];
#pragma unroll
    for (int i = 0; i < 2; ++i) {
#pragma unroll
      for (int r = 0; r < 16; ++r) {
        int m = m0 + i * 32 + (r & 3) + 8 * (r >> 2);
        C[(size_t)m * N + nn] = f2bf(acc[i][j][r] + bv);
      }
    }
  }
}

// ---------------------------------------------------------------------------
// Simple GEMM (small Out layer): C = bf16(A@Bt^T + bias).
// BM x BN tile, BK=32, 256 threads = 4 waves, 32x32x16 MFMA, chunk swizzle.
// GRID MUST BE (32,8,1) -> supertile remap: XCD c owns 4M x 8N tiles.
// ---------------------------------------------------------------------------
template <int BM, int BN, int WR, int WC>
__global__ __launch_bounds__(256) void gemm_bias(
    const unsigned short* __restrict__ A, const unsigned short* __restrict__ Bt,
    const float* __restrict__ bias, unsigned short* __restrict__ C,
    int N, int K, long sA, long sB, long sBias, long sC) {
  constexpr int TM = BM / WR, TN = BN / WC;   // per-wave tile
  constexpr int IM = TM / 32, JN = TN / 32;   // 32x32 frags per wave

  // XCD supertile remap for grid (32,8,1): d&7 -> XCD; each XCD gets
  // mt in [c*4, c*4+4), nt in [0,8). Bijective for 256 wgs.
  const int d = blockIdx.x + 32 * blockIdx.y;
  const int xc = d & 7, kk = d >> 3;
  const int mt = (xc << 2) + (kk >> 3);
  const int nt = kk & 7;

  int e = blockIdx.z;
  A += (size_t)e * sA;
  Bt += (size_t)e * sB;
  bias += (size_t)e * sBias;
  C += (size_t)e * sC;

  __shared__ unsigned short As[BM * 32];
  __shared__ unsigned short Bs[BN * 32];

  int t = threadIdx.x;
  int wave = t >> 6, lane = t & 63;
  int wr = wave / WC, wc = wave % WC;
  int lrow = lane & 31;        // row within 32x32 frag
  int h = lane >> 5;           // k-half selector
  int lsw = (lrow >> 1) & 3;   // row swizzle key

  int srow = t >> 2;
  int schunk = (t & 3) ^ ((t >> 3) & 3);
  const unsigned short* ag = A + (size_t)(mt * BM + srow) * K + schunk * 8;
  const unsigned short* bg = Bt + (size_t)(nt * BN + srow) * K + schunk * 8;
  unsigned short* al = As + t * 8;
  unsigned short* bl = Bs + t * 8;

  f32x16 acc[IM][JN];
#pragma unroll
  for (int i = 0; i < IM; i++)
#pragma unroll
    for (int j = 0; j < JN; j++)
#pragma unroll
      for (int r = 0; r < 16; r++) acc[i][j][r] = 0.f;

  int nk = K >> 5;
  for (int kt = 0; kt < nk; ++kt) {
    __syncthreads();
#pragma unroll
    for (int c = 0; c < BM / 64; ++c)
      __builtin_amdgcn_global_load_lds(
          (const __attribute__((address_space(1))) void*)(ag + (size_t)(64 * c) * K),
          (__attribute__((address_space(3))) void*)(al + 64 * c * 32), 16, 0, 0);
#pragma unroll
    for (int c = 0; c < BN / 64; ++c)
      __builtin_amdgcn_global_load_lds(
          (const __attribute__((address_space(1))) void*)(bg + (size_t)(64 * c) * K),
          (__attribute__((address_space(3))) void*)(bl + 64 * c * 32), 16, 0, 0);
    ag += 32;
    bg += 32;
    __syncthreads();

#pragma unroll
    for (int s = 0; s < 2; ++s) {
      int pc = ((2 * s + h) ^ lsw) * 8;
      short8 af[IM], bf[JN];
#pragma unroll
      for (int i = 0; i < IM; i++)
        af[i] = *(const short8*)(As + (wr * TM + i * 32 + lrow) * 32 + pc);
#pragma unroll
      for (int j = 0; j < JN; j++)
        bf[j] = *(const short8*)(Bs + (wc * TN + j * 32 + lrow) * 32 + pc);
#pragma unroll
      for (int i = 0; i < IM; i++)
#pragma unroll
        for (int j = 0; j < JN; j++)
          acc[i][j] = __builtin_amdgcn_mfma_f32_32x32x16_bf16(af[i], bf[j], acc[i][j], 0, 0, 0);
    }
  }

  int m0 = mt * BM + wr * TM + 4 * h;
  int n0 = nt * BN + wc * TN + lrow;
#pragma unroll
  for (int j = 0; j < JN; j++) {
    int n = n0 + j * 32;
    float bv = bias[n];
#pragma unroll
    for (int i = 0; i < IM; i++) {
#pragma unroll
      for (int r = 0; r < 16; r++) {
        int m = m0 + i * 32 + (r & 3) + 8 * (r >> 2);
        C[(size_t)m * N + n] = f2bf(acc[i][j][r] + bv);
      }
    }
  }
}

// ---------------------------------------------------------------------------
// gelu + row LayerNorm, bf16 in -> bf16 out. grid (B, E), 256 thr, N=256*NPT.
// ---------------------------------------------------------------------------
template <int NPT>
__global__ __launch_bounds__(256) void gelu_ln(const unsigned short* __restrict__ T,
                                               const float* __restrict__ g,
                                               const float* __restrict__ be,
                                               unsigned short* __restrict__ H,
                                               long sT, long sH, int sP) {
  typedef short vecS __attribute__((ext_vector_type(NPT)));
  constexpr int N = 256 * NPT;
  int e = blockIdx.y;
  size_t row = blockIdx.x;
  int t = threadIdx.x;
  const unsigned short* tp = T + (size_t)e * sT + row * N + t * NPT;
  const float* gp = g + (size_t)e * sP + t * NPT;
  const float* bp = be + (size_t)e * sP + t * NPT;
  unsigned short* hp = H + (size_t)e * sH + row * N + t * NPT;

  vecS rv = *(const vecS*)tp;
  float v[NPT], s = 0.f, q = 0.f;
#pragma unroll
  for (int i = 0; i < NPT; i++) {
    v[i] = gelu_erf(bf2f((unsigned short)rv[i]));
    s += v[i];
    q += v[i] * v[i];
  }
#pragma unroll
  for (int off = 32; off > 0; off >>= 1) {
    s += __shfl_down(s, off, 64);
    q += __shfl_down(q, off, 64);
  }
  __shared__ float rs[4], rq[4];
  int wv = t >> 6;
  if ((t & 63) == 0) { rs[wv] = s; rq[wv] = q; }
  __syncthreads();
  s = rs[0] + rs[1] + rs[2] + rs[3];
  q = rq[0] + rq[1] + rq[2] + rq[3];
  float m = s * (1.f / N);
  float rstd = rsqrtf(q * (1.f / N) - m * m + 1e-5f);
  vecS ov;
#pragma unroll
  for (int i = 0; i < NPT; i++)
    ov[i] = (short)f2bf((v[i] - m) * rstd * gp[i] + bp[i]);
  *(vecS*)hp = ov;
}

// ---------------------------------------------------------------------------
// gelu + LN both experts' t3 rows + combine 0.5*(a+b) -> bf16. N=1024 fixed.
// ---------------------------------------------------------------------------
__global__ __launch_bounds__(256) void ln3_combine(const unsigned short* __restrict__ T,
                                                   const float* __restrict__ g,
                                                   const float* __restrict__ be,
                                                   unsigned short* __restrict__ CB) {
  size_t row = blockIdx.x;
  int t = threadIdx.x;
  const unsigned short* t0 = T + row * 1024 + t * 4;
  const unsigned short* t1 = T + (size_t)4096 * 1024 + row * 1024 + t * 4;
  ushort4 r0 = *(const ushort4*)t0;
  ushort4 r1 = *(const ushort4*)t1;
  float v0[4], v1[4];
  v0[0] = gelu_erf(bf2f(r0.x)); v0[1] = gelu_erf(bf2f(r0.y));
  v0[2] = gelu_erf(bf2f(r0.z)); v0[3] = gelu_erf(bf2f(r0.w));
  v1[0] = gelu_erf(bf2f(r1.x)); v1[1] = gelu_erf(bf2f(r1.y));
  v1[2] = gelu_erf(bf2f(r1.z)); v1[3] = gelu_erf(bf2f(r1.w));
  float s0 = 0.f, q0 = 0.f, s1 = 0.f, q1 = 0.f;
#pragma unroll
  for (int i = 0; i < 4; i++) {
    s0 += v0[i]; q0 += v0[i] * v0[i];
    s1 += v1[i]; q1 += v1[i] * v1[i];
  }
#pragma unroll
  for (int off = 32; off > 0; off >>= 1) {
    s0 += __shfl_down(s0, off, 64); q0 += __shfl_down(q0, off, 64);
    s1 += __shfl_down(s1, off, 64); q1 += __shfl_down(q1, off, 64);
  }
  __shared__ float r[4][4];
  int wv = t >> 6;
  if ((t & 63) == 0) { r[0][wv] = s0; r[1][wv] = q0; r[2][wv] = s1; r[3][wv] = q1; }
  __syncthreads();
  s0 = r[0][0] + r[0][1] + r[0][2] + r[0][3];
  q0 = r[1][0] + r[1][1] + r[1][2] + r[1][3];
  s1 = r[2][0] + r[2][1] + r[2][2] + r[2][3];
  q1 = r[3][0] + r[3][1] + r[3][2] + r[3][3];
  float m0 = s0 * (1.f / 1024.f), m1 = s1 * (1.f / 1024.f);
  float rs0 = rsqrtf(q0 * (1.f / 1024.f) - m0 * m0 + 1e-5f);
  float rs1 = rsqrtf(q1 * (1.f / 1024.f) - m1 * m1 + 1e-5f);
  int n = t * 4;
  ushort4 o;
  float a, b;
  a = (v0[0] - m0) * rs0 * g[n + 0] + be[n + 0];
  b = (v1[0] - m1) * rs1 * g[1024 + n + 0] + be[1024 + n + 0];
  o.x = f2bf(0.5f * (a + b));
  a = (v0[1] - m0) * rs0 * g[n + 1] + be[n + 1];
  b = (v1[1] - m1) * rs1 * g[1024 + n + 1] + be[1024 + n + 1];
  o.y = f2bf(0.5f * (a + b));
  a = (v0[2] - m0) * rs0 * g[n + 2] + be[n + 2];
  b = (v1[2] - m1) * rs1 * g[1024 + n + 2] + be[1024 + n + 2];
  o.z = f2bf(0.5f * (a + b));
  a = (v0[3] - m0) * rs0 * g[n + 3] + be[n + 3];
  b = (v1[3] - m1) * rs1 * g[1024 + n + 3] + be[1024 + n + 3];
  o.w = f2bf(0.5f * (a + b));
  *(ushort4*)(CB + row * 1024 + n) = o;
}

// ---------------------------------------------------------------------------
// Final gelu + LN (bf16 in -> f32 out) + ent_loss constant. N=512 fixed.
// ---------------------------------------------------------------------------
__global__ __launch_bounds__(256) void lno_kernel(const unsigned short* __restrict__ T,
                                                  const float* __restrict__ g,
                                                  const float* __restrict__ be,
                                                  float* __restrict__ out) {
  size_t row = blockIdx.x;
  int t = threadIdx.x;
  const unsigned short* tp = T + row * 512 + t * 2;
  ushort2 rv = *(const ushort2*)tp;
  float v[2];
  v[0] = gelu_erf(bf2f(rv.x));
  v[1] = gelu_erf(bf2f(rv.y));
  float s = v[0] + v[1];
  float q = v[0] * v[0] + v[1] * v[1];
#pragma unroll
  for (int off = 32; off > 0; off >>= 1) {
    s += __shfl_down(s, off, 64);
    q += __shfl_down(q, off, 64);
  }
  __shared__ float rs[4], rq[4];
  int wv = t >> 6;
  if ((t & 63) == 0) { rs[wv] = s; rq[wv] = q; }
  __syncthreads();
  s = rs[0] + rs[1] + rs[2] + rs[3];
  q = rq[0] + rq[1] + rq[2] + rq[3];
  float m = s * (1.f / 512.f);
  float rstd = rsqrtf(q * (1.f / 512.f) - m * m + 1e-5f);
  int n = t * 2;
  float2 o;
  o.x = (v[0] - m) * rstd * g[n] + be[n];
  o.y = (v[1] - m) * rstd * g[n + 1] + be[n + 1];
  *(float2*)(out + row * 512 + n) = o;
  if (row == 0 && t == 0) out[(size_t)4096 * 512] = 1.03972077f;  // 1.5*ln(2)
}

// ---------------------------------------------------------------------------
extern "C" void kernel_launch(void* const* d_in, const int* in_sizes, int n_in,
                              void* d_out, int out_size, void* d_ws, size_t ws_size,
                              hipStream_t stream) {
  const float* x   = (const float*)d_in[0];
  const float* W1  = (const float*)d_in[3];
  const float* b1  = (const float*)d_in[4];
  const float* g1  = (const float*)d_in[5];
  const float* be1 = (const float*)d_in[6];
  const float* W2  = (const float*)d_in[7];
  const float* b2  = (const float*)d_in[8];
  const float* g2  = (const float*)d_in[9];
  const float* be2 = (const float*)d_in[10];
  const float* W3  = (const float*)d_in[11];
  const float* b3  = (const float*)d_in[12];
  const float* g3  = (const float*)d_in[13];
  const float* be3 = (const float*)d_in[14];
  const float* Wo  = (const float*)d_in[15];
  const float* bo  = (const float*)d_in[16];
  const float* go  = (const float*)d_in[17];
  const float* beo = (const float*)d_in[18];
  float* out = (float*)d_out;

  char* w = (char*)d_ws;
  unsigned short* xb  = (unsigned short*)(w + 0);          // 8 MB   [4096,1024]
  unsigned short* W1t = (unsigned short*)(w + 8388608);    // 8 MB   [2][2048,1024]
  unsigned short* W2t = (unsigned short*)(w + 16777216);   // 16 MB  [2][2048,2048]
  unsigned short* W3t = (unsigned short*)(w + 33554432);   // 8 MB   [2][1024,2048]
  unsigned short* Wot = (unsigned short*)(w + 41943040);   // 1 MB   [512,1024]
  unsigned short* tR  = (unsigned short*)(w + 42991616);   // 33.5MB [2][4096,2048] raw
  unsigned short* hA  = (unsigned short*)(w + 76546048);   // 33.5MB [2][4096,2048] LN'd
  unsigned short* cb  = (unsigned short*)(w + 110100480);  // 8 MB   [4096,1024]
  unsigned short* to  = (unsigned short*)(w + 118489088);  // 4 MB   [4096,512]

  dim3 tb(32, 8);
  cvt_kernel<<<4096, 256, 0, stream>>>(x, xb);
  transpose_cvt<<<dim3(64, 32, 2), tb, 0, stream>>>(W1, W1t, 1024, 2048);
  transpose_cvt<<<dim3(64, 64, 2), tb, 0, stream>>>(W2, W2t, 2048, 2048);
  transpose_cvt<<<dim3(32, 64, 2), tb, 0, stream>>>(W3, W3t, 2048, 1024);
  transpose_cvt<<<dim3(16, 32, 1), tb, 0, stream>>>(Wo, Wot, 1024, 512);

  // L1: [4096,1024]@[1024,2048] x2 experts — 256x256 tile, 256 blocks (1/CU)
  gemm_pipe<256, 1024><<<dim3(16, 8, 2), 512, 0, stream>>>(
      xb, W1t, b1, tR, 2048, 0L, 2097152L, 2048L, 8388608L);
  gelu_ln<8><<<dim3(4096, 2), 256, 0, stream>>>(tR, g1, be1, hA, 8388608L, 8388608L, 2048);
  // L2: [4096,2048]@[2048,2048] x2 — 256x256 tile
  gemm_pipe<256, 2048><<<dim3(16, 8, 2), 512, 0, stream>>>(
      hA, W2t, b2, tR, 2048, 8388608L, 4194304L, 2048L, 8388608L);
  gelu_ln<8><<<dim3(4096, 2), 256, 0, stream>>>(tR, g2, be2, hA, 8388608L, 8388608L, 2048);
  // L3: [4096,2048]@[2048,1024] x2 — 256x128 tile
  gemm_pipe<128, 2048><<<dim3(16, 8, 2), 512, 0, stream>>>(
      hA, W3t, b3, tR, 1024, 8388608L, 2097152L, 1024L, 4194304L);
  ln3_combine<<<4096, 256, 0, stream>>>(tR, g3, be3, cb);
  // Out: [4096,1024]@[1024,512] — 128x64 tile, 256 blocks (1/CU)
  gemm_bias<128, 64, 2, 2><<<dim3(32, 8, 1), 256, 0, stream>>>(
      cb, Wot, bo, to, 512, 1024, 0L, 0L, 0L, 0L);
  lno_kernel<<<4096, 256, 0, stream>>>(to, go, beo, out);
}